// Round 12
// baseline (468.365 us; speedup 1.0000x reference)
//
#include <hip/hip_runtime.h>

#define EMB 64
#define NS 8            // col slices: 18750 nodes = 2.29 MB bf16 X per slice
#define SLK 229065u     // ceil(2^32/18750): slice = __umulhi(col, SLK)
#define NWG 1024        // exactly-resident grid: 4 WGs per CU
#define GPB 32          // 8-lane groups per 256-thread block
#define TOTG (NWG * GPB)
#define MAXR 5          // ceil(150000 / 32768)

// --- bf16 helpers (RNE) ---
__device__ __forceinline__ float bl(unsigned int u) { return __uint_as_float(u << 16); }
__device__ __forceinline__ float bh(unsigned int u) { return __uint_as_float(u & 0xffff0000u); }
__device__ __forceinline__ unsigned int pack2(float a, float b) {
    unsigned int ua = __float_as_uint(a); ua += 0x7fffu + ((ua >> 16) & 1u);
    unsigned int ub = __float_as_uint(b); ub += 0x7fffu + ((ub >> 16) & 1u);
    return (ua >> 16) | (ub & 0xffff0000u);
}

// Build CSR row pointers from the sorted row array.
__global__ void __launch_bounds__(256) k_rowptr(const int* __restrict__ row,
                                                int* __restrict__ ptr, int E, int R) {
    int e = blockIdx.x * blockDim.x + threadIdx.x;
    if (e >= E) return;
    int r = row[e];
    int prev = (e == 0) ? -1 : row[e - 1];
    for (int q = prev + 1; q <= r; ++q) ptr[q] = e;
    if (e == E - 1) {
        for (int q = r + 1; q <= R; ++q) ptr[q] = E;
    }
}

// X0 = bf16(emb). One thread handles 8 elems.
__global__ void __launch_bounds__(256) k_prep(const float* __restrict__ emb,
                                              uint4* __restrict__ Xb, int n8) {
    int i = blockIdx.x * blockDim.x + threadIdx.x;
    if (i >= n8) return;
    const float4* p = reinterpret_cast<const float4*>(emb) + (size_t)i * 2;
    float4 a = p[0], b = p[1];
    uint4 x;
    x.x = pack2(a.x, a.y); x.y = pack2(a.z, a.w);
    x.z = pack2(b.x, b.y); x.w = pack2(b.z, b.w);
    Xb[i] = x;
}

// Per-row counting sort of edges into NS col-slices.
// E2[s..e) = (col, val-bits) bucketed by slice; cntg[row] = 8 packed byte counts.
// All LDS traffic for a row comes from its own 8-lane group (one wave) -> DS
// ops are wave-ordered, no __syncthreads needed.
__global__ void __launch_bounds__(256) k_bucket(const int* __restrict__ ptr,
                                                const int* __restrict__ col,
                                                const float* __restrict__ vals,
                                                uint2* __restrict__ E2,
                                                uint2* __restrict__ cntg, int R) {
    __shared__ int cnt[GPB][NS];
    int lg = threadIdx.x >> 3;
    int gl = threadIdx.x & 7;
    cnt[lg][gl] = 0;                    // 8 lanes x 8 buckets
    int g = blockIdx.x * GPB + lg;
    if (g >= R) return;
    int s = ptr[g], e = ptr[g + 1];

    // pass 1: count
    for (int i = s + gl; i < e; i += 8) {
        unsigned c = (unsigned)col[i];
        atomicAdd(&cnt[lg][__umulhi(c, SLK)], 1);
    }
    // read counts (wave-ordered after the atomics)
    int cl[NS];
    #pragma unroll
    for (int k = 0; k < NS; ++k) cl[k] = cnt[lg][k];
    // lane gl's bucket base (static indexing only)
    int mypb = 0;
    #pragma unroll
    for (int k = 0; k < NS; ++k) mypb += (k < gl) ? cl[k] : 0;
    cnt[lg][gl] = mypb;                 // counters become running cursors
    if (gl == 0) {
        uint2 pc;
        pc.x = (unsigned)cl[0] | ((unsigned)cl[1] << 8) |
               ((unsigned)cl[2] << 16) | ((unsigned)cl[3] << 24);
        pc.y = (unsigned)cl[4] | ((unsigned)cl[5] << 8) |
               ((unsigned)cl[6] << 16) | ((unsigned)cl[7] << 24);
        cntg[g] = pc;
    }
    // pass 2: scatter
    for (int i = s + gl; i < e; i += 8) {
        unsigned c = (unsigned)col[i];
        float    v = vals[i];
        int k = atomicAdd(&cnt[lg][__umulhi(c, SLK)], 1);
        E2[(size_t)s + k] = make_uint2(c, __float_as_uint(v));
    }
}

// Sliced CSR SpMM. Exactly-resident grid (NWG blocks); each 8-lane group owns
// up to MAXR rows, accumulators in registers across the outer slice loop, so
// the whole GPU sweeps col-slices in near-lockstep: each XCD's random gathers
// stay inside a ~2.3 MB L2-resident slice of Xb.
//   FINAL=0: Yb[row] = bf16(acc)
//   FINAL=1: out[row] = 0.25f * (bf(X0)+bf(X1)+bf(X2) + acc)
template <int FINAL>
__global__ void __launch_bounds__(256, 4) k_spmm3(const int* __restrict__ ptr,
                                                  const uint2* __restrict__ E2,
                                                  const uint2* __restrict__ cntg,
                                                  const uint4* __restrict__ Xb,
                                                  uint4* __restrict__ Yb,
                                                  const uint4* __restrict__ X0,
                                                  const uint4* __restrict__ X1,
                                                  const uint4* __restrict__ X2,
                                                  float* __restrict__ out, int R) {
    int gid = blockIdx.x * GPB + (threadIdx.x >> 3);
    int gl  = threadIdx.x & 7;

    int   rS[MAXR];
    int   cur[MAXR];
    uint2 rc[MAXR];
    float acc[MAXR][8];

    #pragma unroll
    for (int k = 0; k < MAXR; ++k) {
        int r = gid + k * TOTG;
        bool va = r < R;
        int rr = va ? r : 0;
        rS[k] = ptr[rr];
        uint2 t = cntg[rr];
        rc[k].x = va ? t.x : 0u;
        rc[k].y = va ? t.y : 0u;
        cur[k] = 0;
        #pragma unroll
        for (int j = 0; j < 8; ++j) acc[k][j] = 0.f;
    }

    for (int b = 0; b < NS; ++b) {
        #pragma unroll
        for (int k = 0; k < MAXR; ++k) {
            unsigned pc = (b & 4) ? rc[k].y : rc[k].x;
            int len = (int)((pc >> ((b & 3) * 8)) & 0xffu);
            int sseg = rS[k] + cur[k];
            cur[k] += len;
            for (int base2 = 0; base2 < len; base2 += 8) {
                int idx = sseg + base2 + gl;
                int lim = sseg + len - 1;
                idx = idx < lim ? idx : lim;        // clamp inside segment
                uint2 cv = E2[idx];
                unsigned cjv[8];
                float    w[8];
                #pragma unroll
                for (int j = 0; j < 8; ++j) {
                    cjv[j] = (unsigned)__shfl((int)cv.x, j, 8);
                    float vj = __int_as_float(__shfl((int)cv.y, j, 8));
                    w[j] = (base2 + j < len) ? vj : 0.f;
                }
                uint4 xv[8];
                #pragma unroll
                for (int j = 0; j < 8; ++j)
                    xv[j] = Xb[(size_t)cjv[j] * 8u + (unsigned)gl];
                #pragma unroll
                for (int j = 0; j < 8; ++j) {
                    acc[k][0] = fmaf(w[j], bl(xv[j].x), acc[k][0]);
                    acc[k][1] = fmaf(w[j], bh(xv[j].x), acc[k][1]);
                    acc[k][2] = fmaf(w[j], bl(xv[j].y), acc[k][2]);
                    acc[k][3] = fmaf(w[j], bh(xv[j].y), acc[k][3]);
                    acc[k][4] = fmaf(w[j], bl(xv[j].z), acc[k][4]);
                    acc[k][5] = fmaf(w[j], bh(xv[j].z), acc[k][5]);
                    acc[k][6] = fmaf(w[j], bl(xv[j].w), acc[k][6]);
                    acc[k][7] = fmaf(w[j], bh(xv[j].w), acc[k][7]);
                }
            }
        }
    }

    #pragma unroll
    for (int k = 0; k < MAXR; ++k) {
        int r = gid + k * TOTG;
        if (r >= R) continue;
        if (FINAL) {
            size_t o = (size_t)r * 8 + gl;
            uint4 x0 = X0[o], x1 = X1[o], x2 = X2[o];
            float4 o0, o1;
            o0.x = 0.25f * (bl(x0.x) + bl(x1.x) + bl(x2.x) + acc[k][0]);
            o0.y = 0.25f * (bh(x0.x) + bh(x1.x) + bh(x2.x) + acc[k][1]);
            o0.z = 0.25f * (bl(x0.y) + bl(x1.y) + bl(x2.y) + acc[k][2]);
            o0.w = 0.25f * (bh(x0.y) + bh(x1.y) + bh(x2.y) + acc[k][3]);
            o1.x = 0.25f * (bl(x0.z) + bl(x1.z) + bl(x2.z) + acc[k][4]);
            o1.y = 0.25f * (bh(x0.z) + bh(x1.z) + bh(x2.z) + acc[k][5]);
            o1.z = 0.25f * (bl(x0.w) + bl(x1.w) + bl(x2.w) + acc[k][6]);
            o1.w = 0.25f * (bh(x0.w) + bh(x1.w) + bh(x2.w) + acc[k][7]);
            float4* q = reinterpret_cast<float4*>(out + (size_t)r * EMB + gl * 8);
            q[0] = o0; q[1] = o1;
        } else {
            uint4 y;
            y.x = pack2(acc[k][0], acc[k][1]); y.y = pack2(acc[k][2], acc[k][3]);
            y.z = pack2(acc[k][4], acc[k][5]); y.w = pack2(acc[k][6], acc[k][7]);
            Yb[(size_t)r * 8 + gl] = y;
        }
    }
}

extern "C" void kernel_launch(void* const* d_in, const int* in_sizes, int n_in,
                              void* d_out, int out_size, void* d_ws, size_t ws_size,
                              hipStream_t stream) {
    const float* emb  = (const float*)d_in[0];
    const int*   row  = (const int*)d_in[1];
    const int*   col  = (const int*)d_in[2];
    const float* vals = (const float*)d_in[3];

    int nemb = in_sizes[0];   // n_nodes * 64 = 9,600,000
    int E    = in_sizes[1];   // 4,800,000
    int R    = nemb / EMB;    // 150,000

    // ws layout: X0|X1|X2 bf16 (57.6 MB) | ptr (R+4 ints) | cntg (R uint2) |
    //            E2 (E uint2)   -> ~97.8 MB total
    uint4* X0   = (uint4*)d_ws;                // nemb/8 uint4 each
    uint4* X1   = X0 + nemb / 8;
    uint4* X2   = X1 + nemb / 8;
    int*   ptr  = (int*)(X2 + nemb / 8);
    uint2* cntg = (uint2*)(ptr + ((R + 4) & ~3));
    uint2* E2   = cntg + R;

    dim3 blk(256);
    int gridE    = (E + 255) / 256;
    int gridElem = (nemb / 8 + 255) / 256;
    int gridBkt  = (R + GPB - 1) / GPB;

    k_rowptr<<<gridE, blk, 0, stream>>>(row, ptr, E, R);
    k_prep<<<gridElem, blk, 0, stream>>>(emb, X0, nemb / 8);
    k_bucket<<<gridBkt, blk, 0, stream>>>(ptr, col, vals, E2, cntg, R);

    float* outp = (float*)d_out;
    // layer 1: X0 -> X1
    k_spmm3<0><<<NWG, blk, 0, stream>>>(ptr, E2, cntg, X0, X1,
                                        X0, X1, X2, outp, R);
    // layer 2: X1 -> X2
    k_spmm3<0><<<NWG, blk, 0, stream>>>(ptr, E2, cntg, X1, X2,
                                        X0, X1, X2, outp, R);
    // layer 3 fused finalize: out = 0.25*(X0 + X1 + X2 + A·X2)
    k_spmm3<1><<<NWG, blk, 0, stream>>>(ptr, E2, cntg, X2, X1,
                                        X0, X1, X2, outp, R);
}

// Round 13
// 278.772 us; speedup vs baseline: 1.6801x; 1.6801x over previous
//
#include <hip/hip_runtime.h>

#define EMB 64

// --- bf16 helpers (RNE) ---
__device__ __forceinline__ float bl(unsigned int u) { return __uint_as_float(u << 16); }
__device__ __forceinline__ float bh(unsigned int u) { return __uint_as_float(u & 0xffff0000u); }
__device__ __forceinline__ unsigned int pack2(float a, float b) {
    unsigned int ua = __float_as_uint(a); ua += 0x7fffu + ((ua >> 16) & 1u);
    unsigned int ub = __float_as_uint(b); ub += 0x7fffu + ((ub >> 16) & 1u);
    return (ua >> 16) | (ub & 0xffff0000u);
}

// Build CSR row pointers from the sorted row array.
__global__ void __launch_bounds__(256) k_rowptr(const int* __restrict__ row,
                                                int* __restrict__ ptr, int E, int R) {
    int e = blockIdx.x * blockDim.x + threadIdx.x;
    if (e >= E) return;
    int r = row[e];
    int prev = (e == 0) ? -1 : row[e - 1];
    for (int q = prev + 1; q <= r; ++q) ptr[q] = e;
    if (e == E - 1) {
        for (int q = r + 1; q <= R; ++q) ptr[q] = E;
    }
}

// X0 = bf16(emb). One thread handles 8 elems.
__global__ void __launch_bounds__(256) k_prep(const float* __restrict__ emb,
                                              uint4* __restrict__ Xb, int n8) {
    int i = blockIdx.x * blockDim.x + threadIdx.x;
    if (i >= n8) return;
    const float4* p = reinterpret_cast<const float4*>(emb) + (size_t)i * 2;
    float4 a = p[0], b = p[1];
    uint4 x;
    x.x = pack2(a.x, a.y); x.y = pack2(a.z, a.w);
    x.z = pack2(b.x, b.y); x.w = pack2(b.z, b.w);
    Xb[i] = x;
}

__device__ __forceinline__ void loadcv(const int* __restrict__ col,
                                       const float* __restrict__ vals,
                                       int idx, int lim, int& c, float& v) {
    int i = idx < lim ? idx : lim - 1;
    c = col[i];
    v = (idx < lim) ? vals[i] : 0.f;
}

// CSR SpMM, one 8-lane group per row; lane owns 8 dims (one uint4 = 8 bf16).
// 16-edge batches: shuffle-broadcast edge data, issue the 16 gathers before
// the FMA phase, prefetch next batch's edges.
//   FINAL=0: Yb[row] = bf16(acc)
//   FINAL=1: out[row] = 0.25f * (bf(X0[row]) + bf(Xa[row]) + bf(Xc[row]) + acc)
template <int FINAL>
__global__ void __launch_bounds__(256, 3) k_spmm(const int* __restrict__ ptr,
                                                 const int* __restrict__ col,
                                                 const float* __restrict__ vals,
                                                 const uint4* __restrict__ Xb,
                                                 uint4* __restrict__ Yb,
                                                 const uint4* __restrict__ X0,
                                                 const uint4* __restrict__ Xa,
                                                 const uint4* __restrict__ Xc,
                                                 float* __restrict__ out, int R) {
    int tid = blockIdx.x * blockDim.x + threadIdx.x;
    int g   = tid >> 3;       // row id
    int gl  = tid & 7;        // lane in group: dims [8*gl, 8*gl+8)
    if (g >= R) return;

    int s = ptr[g];
    int e = ptr[g + 1];

    float acc0 = 0.f, acc1 = 0.f, acc2 = 0.f, acc3 = 0.f;
    float acc4 = 0.f, acc5 = 0.f, acc6 = 0.f, acc7 = 0.f;

    if (s < e) {
        int   c0, c1;
        float v0, v1;
        loadcv(col, vals, s + gl,     e, c0, v0);
        loadcv(col, vals, s + 8 + gl, e, c1, v1);

        for (int base = s; base < e; base += 16) {
            // A: broadcast 16 edges across the 8-lane group (v already 0 for OOB)
            int   cj[16];
            float vj[16];
            #pragma unroll
            for (int j = 0; j < 8; ++j) {
                cj[j]     = __shfl(c0, j, 8);
                vj[j]     = __shfl(v0, j, 8);
                cj[8 + j] = __shfl(c1, j, 8);
                vj[8 + j] = __shfl(v1, j, 8);
            }
            // B: issue all 16 row gathers
            uint4 xv[16];
            #pragma unroll
            for (int j = 0; j < 16; ++j)
                xv[j] = Xb[(unsigned)cj[j] * 8u + (unsigned)gl];
            // C: prefetch next batch's edge data
            int nbase = base + 16;
            if (nbase < e) {
                loadcv(col, vals, nbase + gl,     e, c0, v0);
                loadcv(col, vals, nbase + 8 + gl, e, c1, v1);
            }
            // D: accumulate
            #pragma unroll
            for (int j = 0; j < 16; ++j) {
                acc0 = fmaf(vj[j], bl(xv[j].x), acc0);
                acc1 = fmaf(vj[j], bh(xv[j].x), acc1);
                acc2 = fmaf(vj[j], bl(xv[j].y), acc2);
                acc3 = fmaf(vj[j], bh(xv[j].y), acc3);
                acc4 = fmaf(vj[j], bl(xv[j].z), acc4);
                acc5 = fmaf(vj[j], bh(xv[j].z), acc5);
                acc6 = fmaf(vj[j], bl(xv[j].w), acc6);
                acc7 = fmaf(vj[j], bh(xv[j].w), acc7);
            }
        }
    }

    if (FINAL) {
        uint4 x0 = X0[(size_t)g * 8 + gl];
        uint4 x1 = Xa[(size_t)g * 8 + gl];
        uint4 x2 = Xc[(size_t)g * 8 + gl];
        float4 o0, o1;
        o0.x = 0.25f * (bl(x0.x) + bl(x1.x) + bl(x2.x) + acc0);
        o0.y = 0.25f * (bh(x0.x) + bh(x1.x) + bh(x2.x) + acc1);
        o0.z = 0.25f * (bl(x0.y) + bl(x1.y) + bl(x2.y) + acc2);
        o0.w = 0.25f * (bh(x0.y) + bh(x1.y) + bh(x2.y) + acc3);
        o1.x = 0.25f * (bl(x0.z) + bl(x1.z) + bl(x2.z) + acc4);
        o1.y = 0.25f * (bh(x0.z) + bh(x1.z) + bh(x2.z) + acc5);
        o1.z = 0.25f * (bl(x0.w) + bl(x1.w) + bl(x2.w) + acc6);
        o1.w = 0.25f * (bh(x0.w) + bh(x1.w) + bh(x2.w) + acc7);
        float4* q = reinterpret_cast<float4*>(out + (size_t)g * EMB + gl * 8);
        q[0] = o0; q[1] = o1;
    } else {
        uint4 y;
        y.x = pack2(acc0, acc1); y.y = pack2(acc2, acc3);
        y.z = pack2(acc4, acc5); y.w = pack2(acc6, acc7);
        Yb[(size_t)g * 8 + gl] = y;
    }
}

extern "C" void kernel_launch(void* const* d_in, const int* in_sizes, int n_in,
                              void* d_out, int out_size, void* d_ws, size_t ws_size,
                              hipStream_t stream) {
    const float* emb  = (const float*)d_in[0];
    const int*   row  = (const int*)d_in[1];
    const int*   col  = (const int*)d_in[2];
    const float* vals = (const float*)d_in[3];

    int nemb = in_sizes[0];   // n_nodes * 64 = 9,600,000
    int E    = in_sizes[1];   // 4,800,000
    int R    = nemb / EMB;    // 150,000

    // ws layout: X0|X1|X2 bf16 (3 x 19.2 MB) | ptr int  (~58.2 MB)
    uint4* X0  = (uint4*)d_ws;                 // nemb/8 uint4 each
    uint4* X1  = X0 + nemb / 8;
    uint4* X2  = X1 + nemb / 8;
    int*   ptr = (int*)(X2 + nemb / 8);

    dim3 blk(256);
    int gridE    = (E + 255) / 256;
    int gridElem = (nemb / 8 + 255) / 256;
    int gridRows = (R * 8 + 255) / 256;

    k_rowptr<<<gridE, blk, 0, stream>>>(row, ptr, E, R);
    k_prep<<<gridElem, blk, 0, stream>>>(emb, X0, nemb / 8);

    float* outp = (float*)d_out;
    // layer 1: X0 -> X1
    k_spmm<0><<<gridRows, blk, 0, stream>>>(ptr, col, vals, X0, X1,
                                            X0, X0, X0, outp, R);
    // layer 2: X1 -> X2
    k_spmm<0><<<gridRows, blk, 0, stream>>>(ptr, col, vals, X1, X2,
                                            X0, X0, X0, outp, R);
    // layer 3 fused finalize: out = 0.25*(X0 + X1 + X2 + A·X2)
    k_spmm<1><<<gridRows, blk, 0, stream>>>(ptr, col, vals, X2, X1,
                                            X0, X1, X2, outp, R);
}